// Round 1
// baseline (509.800 us; speedup 1.0000x reference)
//
#include <hip/hip_runtime.h>

// Fused SLAYER 2-layer SNN forward.
// Trick: alpha_psp is a per-element LTI filter along T, conv2d_time is a
// per-timestep spatial conv -> they commute. We conv the BINARY input spikes
// (held as bitmasks in registers) and apply psp after the conv.
//
// Per block: 16x16 output tile, batch n = blockIdx.z. Loop t=0..49 with all
// recurrence states in VGPRs; x-bits -> LDS floats -> conv1 -> psp1 -> spike1
// -> LDS -> conv2 -> psp2 -> spike2 -> output bitmask regs. 2 barriers/t.

#define TILE 16
#define XR   22            // TILE + 2*(2+1) halo for conv1 region of conv2 region
#define XST  24            // padded row stride (2-way-only LDS bank aliasing)
#define XPL  (XR * XST)    // 528 floats per channel plane
#define SR   18            // TILE + 2*1
#define SST  24
#define SPL  (SR * SST)    // 432

__global__ __launch_bounds__(256, 2)
void snn_fused(const float* __restrict__ xin,
               const float* __restrict__ w1,
               const float* __restrict__ w2,
               float* __restrict__ out)
{
    __shared__ __align__(16) float xf[4 * XPL];   // x(t) bits as float, 22x22 halo
    __shared__ __align__(16) float s1f[4 * SPL];  // layer-1 spikes(t), 18x18
    __shared__ __align__(16) float wL1[400];      // [ic][dy][dx][oc]
    __shared__ __align__(16) float wL2[144];      // [ic][dy][dx][oc]

    const int tid = threadIdx.x;
    const int n   = blockIdx.z;
    const int Y0  = blockIdx.y * TILE;
    const int X0  = blockIdx.x * TILE;

    // ---- stage weights into LDS, transposed to [ic][dy][dx][oc] ----
    for (int i = tid; i < 400; i += 256) {
        int oc = i & 3, r = i >> 2;
        int ic = r / 25, r2 = r - ic * 25;
        int dy = r2 / 5, dx = r2 - dy * 5;
        wL1[i] = w1[((oc * 4 + ic) * 5 + dy) * 5 + dx];
    }
    if (tid < 144) {
        int oc = tid & 3, r = tid >> 2;
        int ic = r / 9, r2 = r - ic * 9;
        int dy = r2 / 3, dx = r2 - dy * 3;
        wL2[tid] = w2[((oc * 4 + ic) * 3 + dy) * 3 + dx];
    }
    // zero s1f once: out-of-image rim stays 0 forever (conv2 zero padding)
    for (int i = tid; i < 4 * SPL; i += 256) s1f[i] = 0.f;

    // ---- load input spikes for the 22x22 halo region as bitmasks ----
    unsigned xm0[2][4], xm1[2][4];
    int  hidx[2];
    bool hact[2];
#pragma unroll
    for (int s = 0; s < 2; ++s) {
        int hp = tid + s * 256;
        hact[s] = (hp < XR * XR);
        int hy = hp / XR;
        int hx = hp - hy * XR;
        hidx[s] = hy * XST + hx;
        int gy = Y0 + hy - 3, gx = X0 + hx - 3;
        bool inimg = hact[s] && gy >= 0 && gy < 128 && gx >= 0 && gx < 128;
#pragma unroll
        for (int c = 0; c < 4; ++c) {
            unsigned m0 = 0, m1 = 0;
            if (inimg) {
                const float* p = xin + ((size_t)(((n * 4 + c) * 128 + gy) * 128 + gx)) * 50;
#pragma unroll
                for (int j = 0; j < 25; ++j) {
                    float2 v = *(const float2*)(p + 2 * j);
                    unsigned b0 = (v.x != 0.f) ? 1u : 0u;
                    unsigned b1 = (v.y != 0.f) ? 1u : 0u;
                    int k = 2 * j;
                    if (k < 32) m0 |= (b0 << k) | (b1 << (k + 1));
                    else        m1 |= (b0 << (k - 32)) | (b1 << (k - 31));
                }
            }
            xm0[s][c] = m0; xm1[s][c] = m1;
        }
    }

    // ---- conv1-region (18x18) slots: layer-1 states ----
    int  cidx[2];
    bool cact[2];
    float s1a[2][4] = {}, s2a[2][4] = {}, s1b[2][4] = {}, s2b[2][4] = {};
#pragma unroll
    for (int s = 0; s < 2; ++s) {
        int cp = tid + s * 256;
        bool a = (cp < SR * SR);
        int cy = cp / SR;
        int cx = cp - cy * SR;
        int gy = Y0 + cy - 1, gx = X0 + cx - 1;
        cact[s] = a && gy >= 0 && gy < 128 && gx >= 0 && gx < 128;
        cidx[s] = cy * SST + cx;   // XST == SST == 24: same index works for xf reads
    }

    // ---- interior pixel: layer-2 states + output bitmask ----
    const int iy = tid >> 4, ix = tid & 15;
    const int iidx = iy * SST + ix;
    float s1c[4] = {}, s2c[4] = {}, s1d[4] = {}, s2d[4] = {};
    unsigned om0[4] = {}, om1[4] = {};

    const float R1  = 0.36787944117144233f;   // exp(-1/1)
    const float CO1 = 2.7182818284590452f;    // e/1
    const float R2  = 0.60653065971263342f;   // exp(-1/2)
    const float CO2 = 1.3591409142295226f;    // e/2
    const float CRF = -54.365636569180902f;   // -20e == -1*20*e/1 == -1*40*e/2

    for (int t = 0; t < 50; ++t) {
        const bool hi = (t >= 32);
        const int  tb = t & 31;

        // ---- step 1: decode x bit(t) -> xf floats ----
#pragma unroll
        for (int s = 0; s < 2; ++s) {
            if (hact[s]) {
#pragma unroll
                for (int c = 0; c < 4; ++c) {
                    unsigned m = hi ? xm1[s][c] : xm0[s][c];
                    xf[c * XPL + hidx[s]] = (float)((m >> tb) & 1u);
                }
            }
        }
        __syncthreads();

        // ---- step 2: conv1(5x5) + psp1 + spike1 on 18x18 region ----
#pragma unroll
        for (int s = 0; s < 2; ++s) {
            if (cact[s]) {
                float a0 = 0.f, a1 = 0.f, a2 = 0.f, a3 = 0.f;
                const float* xpl = &xf[cidx[s]];
                const float4* wp = (const float4*)wL1;
#pragma unroll 1
                for (int ic = 0; ic < 4; ++ic) {
                    const float* xr = xpl;
#pragma unroll 1
                    for (int dy = 0; dy < 5; ++dy) {
                        float xv0 = xr[0], xv1 = xr[1], xv2 = xr[2], xv3 = xr[3], xv4 = xr[4];
                        float4 w0 = wp[0], w1v = wp[1], w2v = wp[2], w3v = wp[3], w4v = wp[4];
                        a0 = fmaf(xv0, w0.x, a0);  a1 = fmaf(xv0, w0.y, a1);
                        a2 = fmaf(xv0, w0.z, a2);  a3 = fmaf(xv0, w0.w, a3);
                        a0 = fmaf(xv1, w1v.x, a0); a1 = fmaf(xv1, w1v.y, a1);
                        a2 = fmaf(xv1, w1v.z, a2); a3 = fmaf(xv1, w1v.w, a3);
                        a0 = fmaf(xv2, w2v.x, a0); a1 = fmaf(xv2, w2v.y, a1);
                        a2 = fmaf(xv2, w2v.z, a2); a3 = fmaf(xv2, w2v.w, a3);
                        a0 = fmaf(xv3, w3v.x, a0); a1 = fmaf(xv3, w3v.y, a1);
                        a2 = fmaf(xv3, w3v.z, a2); a3 = fmaf(xv3, w3v.w, a3);
                        a0 = fmaf(xv4, w4v.x, a0); a1 = fmaf(xv4, w4v.y, a1);
                        a2 = fmaf(xv4, w4v.z, a2); a3 = fmaf(xv4, w4v.w, a3);
                        xr += XST; wp += 5;
                    }
                    xpl += XPL;
                }
#pragma unroll
                for (int oc = 0; oc < 4; ++oc) {
                    float cc = (oc == 0) ? a0 : (oc == 1) ? a1 : (oc == 2) ? a2 : a3;
                    float ao  = CO1 * s2a[s][oc];              // psp output (pre-update)
                    float ns1 = fmaf(R1, s1a[s][oc], cc);      // s1 = r*s1 + conv
                    s1a[s][oc] = ns1;
                    s2a[s][oc] = fmaf(R1, s2a[s][oc], R1 * ns1);
                    float m  = fmaf(CRF, s2b[s][oc], ao);      // membrane
                    float sp = (m >= 20.f) ? 1.f : 0.f;
                    float nb1 = fmaf(R1, s1b[s][oc], sp);
                    s1b[s][oc] = nb1;
                    s2b[s][oc] = fmaf(R1, s2b[s][oc], R1 * nb1);
                    s1f[oc * SPL + cidx[s]] = sp;
                }
            }
        }
        __syncthreads();

        // ---- step 3: conv2(3x3) + psp2 + spike2 on interior 16x16 ----
        {
            float a0 = 0.f, a1 = 0.f, a2 = 0.f, a3 = 0.f;
            const float* spl = &s1f[iidx];
            const float4* wp = (const float4*)wL2;
#pragma unroll 1
            for (int ic = 0; ic < 4; ++ic) {
                const float* xr = spl;
#pragma unroll 1
                for (int dy = 0; dy < 3; ++dy) {
                    float xv0 = xr[0], xv1 = xr[1], xv2 = xr[2];
                    float4 w0 = wp[0], w1v = wp[1], w2v = wp[2];
                    a0 = fmaf(xv0, w0.x, a0);  a1 = fmaf(xv0, w0.y, a1);
                    a2 = fmaf(xv0, w0.z, a2);  a3 = fmaf(xv0, w0.w, a3);
                    a0 = fmaf(xv1, w1v.x, a0); a1 = fmaf(xv1, w1v.y, a1);
                    a2 = fmaf(xv1, w1v.z, a2); a3 = fmaf(xv1, w1v.w, a3);
                    a0 = fmaf(xv2, w2v.x, a0); a1 = fmaf(xv2, w2v.y, a1);
                    a2 = fmaf(xv2, w2v.z, a2); a3 = fmaf(xv2, w2v.w, a3);
                    xr += SST; wp += 3;
                }
                spl += SPL;
            }
#pragma unroll
            for (int oc = 0; oc < 4; ++oc) {
                float cc = (oc == 0) ? a0 : (oc == 1) ? a1 : (oc == 2) ? a2 : a3;
                float ao  = CO2 * s2c[oc];
                float ns1 = fmaf(R2, s1c[oc], cc);
                s1c[oc] = ns1;
                s2c[oc] = fmaf(R2, s2c[oc], R2 * ns1);
                float m = fmaf(CRF, s2d[oc], ao);
                unsigned b = (m >= 40.f) ? 1u : 0u;
                float sp = (float)b;
                float nd1 = fmaf(R2, s1d[oc], sp);
                s1d[oc] = nd1;
                s2d[oc] = fmaf(R2, s2d[oc], R2 * nd1);
                if (hi) om1[oc] |= b << tb; else om0[oc] |= b << tb;
            }
        }
        __syncthreads();   // xf(t+1) writes vs step-2 stragglers? covered; this
                           // protects s1f reads in step 3 vs step-2(t+1) writes
                           // is NOT needed (B1 of t+1 covers) -- but keep one
                           // barrier out: see note. (Removed below.)
    }

    // ---- epilogue: expand output bitmasks to floats, 200B/pixel-channel ----
#pragma unroll
    for (int c = 0; c < 4; ++c) {
        float* p = out + ((size_t)(((n * 4 + c) * 128 + (Y0 + iy)) * 128 + (X0 + ix))) * 50;
        unsigned m0 = om0[c], m1 = om1[c];
#pragma unroll
        for (int j = 0; j < 25; ++j) {
            int k = 2 * j;
            float2 v;
            unsigned ma = (k < 32) ? m0 : m1;
            unsigned mb = (k + 1 < 32) ? m0 : m1;
            v.x = (float)((ma >> (k & 31)) & 1u);
            v.y = (float)((mb >> ((k + 1) & 31)) & 1u);
            *(float2*)(p + k) = v;
        }
    }
}

extern "C" void kernel_launch(void* const* d_in, const int* in_sizes, int n_in,
                              void* d_out, int out_size, void* d_ws, size_t ws_size,
                              hipStream_t stream) {
    (void)in_sizes; (void)n_in; (void)out_size; (void)d_ws; (void)ws_size;
    const float* x  = (const float*)d_in[0];
    const float* w1 = (const float*)d_in[1];
    const float* w2 = (const float*)d_in[2];
    float* o = (float*)d_out;
    dim3 grid(128 / TILE, 128 / TILE, 8);   // 8x8 tiles x 8 batch = 512 blocks
    dim3 block(256);
    hipLaunchKernelGGL(snn_fused, grid, block, 0, stream, x, w1, w2, o);
}

// Round 3
// 416.006 us; speedup vs baseline: 1.2255x; 1.2255x over previous
//
#include <hip/hip_runtime.h>

// Fused SLAYER 2-layer SNN forward, time-chunked bitmask version.
//
// psp (per-element LTI filter in t) commutes with the per-timestep spatial
// conv, so we conv the BINARY spikes and apply psp to the conv output.
// All spike tensors live as bitmasks; convs process chunks of TC=10
// timesteps per LDS read of mask+weights (10x fewer LDS instructions than
// per-t float staging), and there are only 2 barriers per chunk (11 total
// vs 150 before). Summation order (ic,dy,dx) and recurrence arithmetic are
// bit-identical to the previous passing kernel.

#define TILE 16
#define R1S  22                 // x-mask region: TILE + 2*(2+1)
#define R1N  (R1S * R1S)        // 484
#define R2S  18                 // layer-1 spike region: TILE + 2*1
#define R2N  (R2S * R2S)        // 324
#define TC   10                 // timesteps per chunk (50 = 5 chunks)

__global__ __launch_bounds__(256)
void snn_fused(const float* __restrict__ xin,
               const float* __restrict__ w1,
               const float* __restrict__ w2,
               float* __restrict__ out)
{
    __shared__ __align__(16) uint2    xm[4][R1N];   // input spike masks (all 50 t)
    __shared__ unsigned               s1m[4][R2N];  // layer-1 spike masks (per chunk)
    __shared__ __align__(16) float    wL1[400];     // [ic][dy][dx][oc]
    __shared__ __align__(16) float    wL2[144];     // [ic][dy][dx][oc]

    const int tid = threadIdx.x;
    const int n   = blockIdx.z;
    const int Y0  = blockIdx.y * TILE;
    const int X0  = blockIdx.x * TILE;

    // ---- stage weights, transposed to [ic][dy][dx][oc] ----
    for (int i = tid; i < 400; i += 256) {
        int oc = i & 3, r = i >> 2;
        int ic = r / 25, r2 = r - ic * 25;
        int dy = r2 / 5, dx = r2 - dy * 5;
        wL1[i] = w1[((oc * 4 + ic) * 5 + dy) * 5 + dx];
    }
    if (tid < 144) {
        int oc = tid & 3, r = tid >> 2;
        int ic = r / 9, r2 = r - ic * 9;
        int dy = r2 / 3, dx = r2 - dy * 3;
        wL2[tid] = w2[((oc * 4 + ic) * 3 + dy) * 3 + dx];
    }

    // ---- pack input spikes (50 floats) into 64-bit masks, once ----
#pragma unroll
    for (int s = 0; s < 2; ++s) {
        int hp = tid + s * 256;
        if (hp < R1N) {
            int hy = hp / R1S, hx = hp - hy * R1S;
            int gy = Y0 + hy - 3, gx = X0 + hx - 3;
            bool inimg = gy >= 0 && gy < 128 && gx >= 0 && gx < 128;
#pragma unroll
            for (int c = 0; c < 4; ++c) {
                unsigned m0 = 0, m1 = 0;
                if (inimg) {
                    const float2* p = (const float2*)
                        (xin + ((size_t)(((n * 4 + c) * 128 + gy) * 128 + gx)) * 50);
#pragma unroll
                    for (int j = 0; j < 25; ++j) {
                        float2 v = p[j];
                        unsigned b0 = (v.x != 0.f) ? 1u : 0u;
                        unsigned b1 = (v.y != 0.f) ? 1u : 0u;
                        int k = 2 * j;
                        if (k < 32) m0 |= (b0 << k) | (b1 << (k + 1));
                        else        m1 |= (b0 << (k - 32)) | (b1 << (k - 31));
                    }
                }
                xm[c][hp] = make_uint2(m0, m1);
            }
        }
    }

    // ---- slot setup for the 18x18 layer-1 region (324 px on 256 lanes) ----
    // slot 1 is rotated by block id so the "heavy" wave differs across the
    // two co-resident blocks on a CU.
    const int rot = (blockIdx.x + blockIdx.y + blockIdx.z) & 3;
    int  cidx[2], xbase[2];
    bool cw[2], cin[2];
#pragma unroll
    for (int s = 0; s < 2; ++s) {
        int cp = (s == 0) ? tid : (((tid + (rot << 6)) & 255) + 256);
        cw[s] = (cp < R2N);
        int cy = cp / R2S;
        int cx = cp - cy * R2S;
        int gy = Y0 + cy - 1, gx = X0 + cx - 1;
        cin[s]  = cw[s] && gy >= 0 && gy < 128 && gx >= 0 && gx < 128;
        cidx[s] = cp;
        xbase[s] = cy * R1S + cx;
    }

    const int iy = tid >> 4, ix = tid & 15;
    const int ibase = iy * R2S + ix;

    // persistent recurrence states
    float s1a[2][4] = {}, s2a[2][4] = {}, s1b[2][4] = {}, s2b[2][4] = {};
    float s1c[4] = {}, s2c[4] = {}, s1d[4] = {}, s2d[4] = {};
    unsigned long long om[4] = {};

    const float R1  = 0.36787944117144233f;   // exp(-1/1)
    const float CO1 = 2.7182818284590452f;    // e/1
    const float R2  = 0.60653065971263342f;   // exp(-1/2)
    const float CO2 = 1.3591409142295226f;    // e/2
    const float CRF = -54.365636569180902f;   // -20e == -40e/2

    __syncthreads();

    for (int chk = 0; chk < 5; ++chk) {
        const int t0 = chk * TC;

        // ================= layer 1: conv1 + psp1 + spike1 =================
#pragma unroll
        for (int s = 0; s < 2; ++s) {
            if (cw[s]) {
                float a[TC][4];
#pragma unroll
                for (int u = 0; u < TC; ++u) { a[u][0]=0.f; a[u][1]=0.f; a[u][2]=0.f; a[u][3]=0.f; }
                if (cin[s]) {
#pragma unroll 1
                    for (int ic = 0; ic < 4; ++ic) {
                        const uint2*  xp = &xm[ic][xbase[s]];
                        const float4* wp = (const float4*)&wL1[ic * 100];
#pragma unroll 1
                        for (int dy = 0; dy < 5; ++dy) {
#pragma unroll
                            for (int dx = 0; dx < 5; ++dx) {
                                uint2 m = xp[dx];
                                unsigned long long mm =
                                    ((unsigned long long)m.y << 32) | m.x;
                                unsigned win = (unsigned)(mm >> t0);
                                float4 w = wp[dx];
#pragma unroll
                                for (int u = 0; u < TC; ++u) {
                                    float f = (float)((win >> u) & 1u);
                                    a[u][0] = fmaf(f, w.x, a[u][0]);
                                    a[u][1] = fmaf(f, w.y, a[u][1]);
                                    a[u][2] = fmaf(f, w.z, a[u][2]);
                                    a[u][3] = fmaf(f, w.w, a[u][3]);
                                }
                            }
                            xp += R1S; wp += 5;
                        }
                    }
                }
                unsigned cm[4] = {0, 0, 0, 0};
#pragma unroll
                for (int u = 0; u < TC; ++u) {
#pragma unroll
                    for (int oc = 0; oc < 4; ++oc) {
                        float ao  = CO1 * s2a[s][oc];
                        float ns1 = fmaf(R1, s1a[s][oc], a[u][oc]);
                        s1a[s][oc] = ns1;
                        s2a[s][oc] = fmaf(R1, s2a[s][oc], R1 * ns1);
                        float mv = fmaf(CRF, s2b[s][oc], ao);
                        unsigned b = (mv >= 20.f) ? 1u : 0u;
                        float spf = (float)b;
                        float nb1 = fmaf(R1, s1b[s][oc], spf);
                        s1b[s][oc] = nb1;
                        s2b[s][oc] = fmaf(R1, s2b[s][oc], R1 * nb1);
                        cm[oc] |= b << u;
                    }
                }
                s1m[0][cidx[s]] = cm[0];
                s1m[1][cidx[s]] = cm[1];
                s1m[2][cidx[s]] = cm[2];
                s1m[3][cidx[s]] = cm[3];
            }
        }
        __syncthreads();

        // ================= layer 2: conv2 + psp2 + spike2 =================
        {
            float a[TC][4];
#pragma unroll
            for (int u = 0; u < TC; ++u) { a[u][0]=0.f; a[u][1]=0.f; a[u][2]=0.f; a[u][3]=0.f; }
#pragma unroll 1
            for (int ic = 0; ic < 4; ++ic) {
                const unsigned* sp = &s1m[ic][ibase];
                const float4*   wp = (const float4*)&wL2[ic * 36];
#pragma unroll 1
                for (int dy = 0; dy < 3; ++dy) {
#pragma unroll
                    for (int dx = 0; dx < 3; ++dx) {
                        unsigned win = sp[dx];
                        float4 w = wp[dx];
#pragma unroll
                        for (int u = 0; u < TC; ++u) {
                            float f = (float)((win >> u) & 1u);
                            a[u][0] = fmaf(f, w.x, a[u][0]);
                            a[u][1] = fmaf(f, w.y, a[u][1]);
                            a[u][2] = fmaf(f, w.z, a[u][2]);
                            a[u][3] = fmaf(f, w.w, a[u][3]);
                        }
                    }
                    sp += R2S; wp += 3;
                }
            }
            unsigned cm[4] = {0, 0, 0, 0};
#pragma unroll
            for (int u = 0; u < TC; ++u) {
#pragma unroll
                for (int oc = 0; oc < 4; ++oc) {
                    float ao  = CO2 * s2c[oc];
                    float ns1 = fmaf(R2, s1c[oc], a[u][oc]);
                    s1c[oc] = ns1;
                    s2c[oc] = fmaf(R2, s2c[oc], R2 * ns1);
                    float mv = fmaf(CRF, s2d[oc], ao);
                    unsigned b = (mv >= 40.f) ? 1u : 0u;
                    float spf = (float)b;
                    float nd1 = fmaf(R2, s1d[oc], spf);
                    s1d[oc] = nd1;
                    s2d[oc] = fmaf(R2, s2d[oc], R2 * nd1);
                    cm[oc] |= b << u;
                }
            }
#pragma unroll
            for (int oc = 0; oc < 4; ++oc)
                om[oc] |= (unsigned long long)cm[oc] << t0;
        }
        __syncthreads();   // protect s1m reads vs next chunk's writes
    }

    // ---- epilogue: expand output bitmasks to floats ----
#pragma unroll
    for (int c = 0; c < 4; ++c) {
        float* p = out + ((size_t)(((n * 4 + c) * 128 + (Y0 + iy)) * 128 + (X0 + ix))) * 50;
        unsigned long long m = om[c];
#pragma unroll
        for (int j = 0; j < 25; ++j) {
            int k = 2 * j;
            float2 v;
            v.x = (float)((unsigned)(m >> k) & 1u);
            v.y = (float)((unsigned)(m >> (k + 1)) & 1u);
            *(float2*)(p + k) = v;
        }
    }
}

extern "C" void kernel_launch(void* const* d_in, const int* in_sizes, int n_in,
                              void* d_out, int out_size, void* d_ws, size_t ws_size,
                              hipStream_t stream) {
    (void)in_sizes; (void)n_in; (void)out_size; (void)d_ws; (void)ws_size;
    const float* x  = (const float*)d_in[0];
    const float* w1 = (const float*)d_in[1];
    const float* w2 = (const float*)d_in[2];
    float* o = (float*)d_out;
    dim3 grid(128 / TILE, 128 / TILE, 8);   // 512 blocks
    dim3 block(256);
    hipLaunchKernelGGL(snn_fused, grid, block, 0, stream, x, w1, w2, o);
}